// Round 1
// baseline (380.882 us; speedup 1.0000x reference)
//
#include <hip/hip_runtime.h>
#include <hip/hip_cooperative_groups.h>
#include <math.h>

namespace cg = cooperative_groups;

#define IC     2401
#define BSZ    256
#define OC     8
#define CS     16
#define OCC    128     // OC*CS
#define XROW   19208   // x row length (floats) = IC*8
#define KP     19264   // padded K (=301*64 = 2408 granules of 8), pad zeroed
#define KTILES 301
#define NI     64      // split-K slices for s phase

typedef __attribute__((ext_vector_type(8))) short short8;
typedef __attribute__((ext_vector_type(4))) float f32x4;

__device__ __forceinline__ unsigned short f2bf(float f) {
    union { float f; unsigned u; } v; v.f = f;
    const unsigned r = v.u + 0x7FFF + ((v.u >> 16) & 1);   // RNE
    return (unsigned short)(r >> 16);
}
__device__ __forceinline__ float bf2f(unsigned short h) {
    union { unsigned u; float f; } v; v.u = ((unsigned)h) << 16;
    return v.f;
}

// ---------------- prep (one launch): blocks 0..1203 -> xT + xB ; 1204..1504 -> Wbf + cwt0
__global__ __launch_bounds__(256)
void prep_kernel(const float* __restrict__ x, const float* __restrict__ W,
                 unsigned short* __restrict__ xT, unsigned short* __restrict__ xB,
                 unsigned short* __restrict__ Wbf, unsigned short* __restrict__ cwt)
{
    const int tid = threadIdx.x;
    if (blockIdx.x < 1204) {
        __shared__ float Ts[64 * 65];
        const int bg = blockIdx.x & 3;       // b-group of 64
        const int kt = blockIdx.x >> 2;      // k-tile 0..300
#pragma unroll
        for (int r = 0; r < 4; ++r) {
            const int flat = r * 256 + tid;  // 1024 float4s
            const int b = flat >> 4, cq = flat & 15;
            const int col = kt * 64 + cq * 4;
            float4 v = make_float4(0.f, 0.f, 0.f, 0.f);
            if (col < XROW) v = *(const float4*)(x + (size_t)(bg * 64 + b) * XROW + col);
            *(float4*)&Ts[b * 65 + cq * 4] = v;
        }
        __syncthreads();
        // xT[k][b] (transposed)
#pragma unroll
        for (int r = 0; r < 2; ++r) {
            const int flat = r * 256 + tid;  // 512 granules
            const int rl = flat >> 3, bq = flat & 7;
            union { short8 v; unsigned short h[8]; } o;
#pragma unroll
            for (int j = 0; j < 8; ++j) o.h[j] = f2bf(Ts[(bq * 8 + j) * 65 + rl]);
            *(short8*)(xT + (size_t)(kt * 64 + rl) * 256 + bg * 64 + bq * 8) = o.v;
        }
        // xB[b][k] (row-major bf16, padded)
#pragma unroll
        for (int r = 0; r < 2; ++r) {
            const int flat = r * 256 + tid;  // 512 granules
            const int b = flat >> 3, g = flat & 7;
            union { short8 v; unsigned short h[8]; } o;
#pragma unroll
            for (int j = 0; j < 8; ++j) o.h[j] = f2bf(Ts[b * 65 + g * 8 + j]);
            *(short8*)(xB + (size_t)(bg * 64 + b) * KP + (size_t)kt * 64 + g * 8) = o.v;
        }
    } else {
        __shared__ float Ws[8 * 1032];
        const int i0 = (blockIdx.x - 1204) * 8;
#pragma unroll
        for (int r = 0; r < 8; ++r) {
            const int flat = r * 256 + tid;  // 2048 float4s
            const int g = flat >> 8, rem = flat & 255;
            int gi = i0 + g; if (gi > 2400) gi = 2400;
            const float4 v = *(const float4*)(W + (size_t)gi * 1024 + rem * 4);
            *(float4*)&Ws[g * 1032 + rem * 4] = v;
        }
        __syncthreads();
#pragma unroll
        for (int r = 0; r < 4; ++r) {
            const int flat = r * 256 + tid;  // 1024 granules
            const int oc = flat >> 3, g = flat & 7;
            const int gi = i0 + g;
            union { short8 v; unsigned short h[8]; } w, c;
            if (gi <= 2400) {
                const float* wp = &Ws[g * 1032 + oc * 8];
#pragma unroll
                for (int j = 0; j < 8; ++j) {
                    w.h[j] = f2bf(wp[j]);
                    c.h[j] = f2bf(0.125f * wp[j]);
                }
            } else {
#pragma unroll
                for (int j = 0; j < 8; ++j) { w.h[j] = 0; c.h[j] = 0; }
            }
            *(short8*)(Wbf + (size_t)oc * KP + (size_t)gi * 8) = w.v;
            *(short8*)(cwt + (size_t)oc * KP + (size_t)gi * 8) = c.v;
        }
    }
}

// ---------------- S phase body: spart[iy][b][oc] = sum_k xB[b,k]*cwt[oc,k]
// bid in [0,256): bg = bid&3 (64 b-rows), iy = bid>>2 (split-K slice).
__device__ __forceinline__ void s_phase(char* smraw, const int tid, const int bid,
        const unsigned short* __restrict__ xB, const unsigned short* __restrict__ cwt,
        float* __restrict__ spart)
{
    unsigned short* Xs = (unsigned short*)smraw;            // 8 KB
    unsigned short* Bs = (unsigned short*)(smraw + 8192);   // 16 KB
    const int bg = bid & 3, iy = bid >> 2;
    const int b0 = bg * 64;
    const int ln = tid & 63;
    const int mr = ln & 15, qd = ln >> 4;
    const int mh = (tid >> 6) & 1;        // m-half (32 b-rows)
    const int nh = tid >> 7;              // n-half (64 oc)

    f32x4 acc[2][4];
#pragma unroll
    for (int a = 0; a < 2; ++a)
#pragma unroll
        for (int b = 0; b < 4; ++b) acc[a][b] = (f32x4){0.f, 0.f, 0.f, 0.f};

    for (int kt = iy; kt < KTILES; kt += NI) {
        __syncthreads();
#pragma unroll
        for (int r = 0; r < 2; ++r) {        // Xs <- xB (pure bf16 copy)
            const int flat = r * 256 + tid;
            const int b = flat >> 3, col = flat & 7;
            const short8 v = *(const short8*)(xB + (size_t)(b0 + b) * KP + (size_t)(kt * 8 + col) * 8);
            *(short8*)&Xs[b * 64 + ((col ^ (b & 7)) * 8)] = v;
        }
#pragma unroll
        for (int r = 0; r < 4; ++r) {        // Bs <- cwt
            const int flat = r * 256 + tid;
            const int oc = flat >> 3, col = flat & 7;
            const short8 w = *(const short8*)(cwt + (size_t)oc * KP + (size_t)(kt * 8 + col) * 8);
            *(short8*)&Bs[oc * 64 + ((col ^ (oc & 7)) * 8)] = w;
        }
        __syncthreads();
#pragma unroll
        for (int kk = 0; kk < 2; ++kk) {
            const int csw = ((kk * 4 + qd) ^ (mr & 7)) * 8;
            const short8 a0 = *(const short8*)&Xs[(mh * 32 + mr) * 64 + csw];
            const short8 a1 = *(const short8*)&Xs[(mh * 32 + 16 + mr) * 64 + csw];
#pragma unroll
            for (int nt = 0; nt < 4; ++nt) {
                const short8 b = *(const short8*)&Bs[(nh * 64 + nt * 16 + mr) * 64 + csw];
                acc[0][nt] = __builtin_amdgcn_mfma_f32_16x16x32_bf16(a0, b, acc[0][nt], 0, 0, 0);
                acc[1][nt] = __builtin_amdgcn_mfma_f32_16x16x32_bf16(a1, b, acc[1][nt], 0, 0, 0);
            }
        }
    }

    float* op = spart + ((size_t)iy * BSZ + b0) * OCC;
#pragma unroll
    for (int mt = 0; mt < 2; ++mt)
#pragma unroll
        for (int nt = 0; nt < 4; ++nt)
#pragma unroll
            for (int r = 0; r < 4; ++r)
                op[(size_t)(mh * 32 + mt * 16 + qd * 4 + r) * OCC + nh * 64 + nt * 16 + mr]
                    = acc[mt][nt][r];
}

// ---------------- Q phase body: reduce NI split-K partials + squash.
// bid in [0,256): 8 (b,o)-rows per block.
__device__ __forceinline__ void q_phase(char* smraw, const int tid, const int bid, const int writeT,
        const float* __restrict__ spart, float* __restrict__ vout, unsigned short* __restrict__ vT)
{
    float* red = (float*)smraw;
    const int r0  = bid * 8;                 // first of 8 rows (row = b*8+o)
    const int idx = tid & 127;               // element within 8x16 chunk
    const int k0  = tid >> 7;                // k parity

    const float* base = spart + (size_t)r0 * 16 + idx;
    float acc = 0.0f;
#pragma unroll 8
    for (int k = k0; k < NI; k += 2) acc += base[(size_t)k * (BSZ * OCC)];
    red[tid] = acc;
    __syncthreads();

    if (tid < 128) {
        const float s = red[tid] + red[tid + 128];
        float ms = s * s;
        ms += __shfl_xor(ms, 1); ms += __shfl_xor(ms, 2);
        ms += __shfl_xor(ms, 4); ms += __shfl_xor(ms, 8);
        const float scale = sqrtf(ms) / (1.0f + ms);   // == mag_sq/(1+mag_sq)/mag
        const float outv = s * scale;
        const int row = r0 + (tid >> 4);     // = b*8 + o
        const int j   = tid & 15;
        if (writeT) {
            vT[(size_t)((row & 7) * 16 + j) * 256 + (row >> 3)] = f2bf(outv);
        } else {
            vout[(size_t)row * 16 + j] = outv;
        }
    }
}

// ---------------- A phase body: agreement (MFMA) + bij + softmax + write cwt.
// t = i-tile index (8 i's per tile).
__device__ __forceinline__ void a_phase(char* smraw, const int tid, const int t, const int first,
        const unsigned short* __restrict__ xT, const unsigned short* __restrict__ vT,
        const unsigned short* __restrict__ Wbf, float* __restrict__ bij,
        unsigned short* __restrict__ cwt)
{
    unsigned short* As = (unsigned short*)smraw;            // [128 oc][64 b]
    unsigned short* Bx = (unsigned short*)(smraw + 16384);  // [64 (i,d)][64 b]
    float* Hs = (float*)smraw;                              // [128][68]

    const int i0  = t * 8;
    const int ln  = tid & 63, wv = tid >> 6;
    const int mr  = ln & 15, qd = ln >> 4;

    f32x4 acc[2][4];
#pragma unroll
    for (int a = 0; a < 2; ++a)
#pragma unroll
        for (int b = 0; b < 4; ++b) acc[a][b] = (f32x4){0.f, 0.f, 0.f, 0.f};

    for (int bc = 0; bc < 4; ++bc) {
        __syncthreads();
#pragma unroll
        for (int r = 0; r < 4; ++r) {          // As <- vT tile
            const int flat = r * 256 + tid;
            const int oc = flat >> 3, col = flat & 7;
            const short8 v = *(const short8*)(vT + (size_t)oc * 256 + bc * 64 + col * 8);
            *(short8*)&As[oc * 64 + ((col ^ (oc & 7)) * 8)] = v;
        }
#pragma unroll
        for (int r = 0; r < 2; ++r) {          // Bx <- xT rows i0*8..+63
            const int flat = r * 256 + tid;
            const int rw = flat >> 3, col = flat & 7;
            const short8 v = *(const short8*)(xT + (size_t)(i0 * 8 + rw) * 256 + bc * 64 + col * 8);
            *(short8*)&Bx[rw * 64 + ((col ^ (rw & 7)) * 8)] = v;
        }
        __syncthreads();
#pragma unroll
        for (int kk = 0; kk < 2; ++kk) {
            const int csw = ((kk * 4 + qd) ^ (mr & 7)) * 8;
#pragma unroll
            for (int nt = 0; nt < 4; ++nt) {
                const short8 b = *(const short8*)&Bx[(nt * 16 + mr) * 64 + csw];
#pragma unroll
                for (int mt = 0; mt < 2; ++mt) {
                    const short8 a = *(const short8*)&As[((wv * 2 + mt) * 16 + mr) * 64 + csw];
                    acc[mt][nt] = __builtin_amdgcn_mfma_f32_16x16x32_bf16(a, b, acc[mt][nt], 0, 0, 0);
                }
            }
        }
    }

    __syncthreads();
#pragma unroll
    for (int mt = 0; mt < 2; ++mt)
#pragma unroll
        for (int nt = 0; nt < 4; ++nt)
#pragma unroll
            for (int r = 0; r < 4; ++r)
                Hs[((wv * 2 + mt) * 16 + qd * 4 + r) * 68 + nt * 16 + mr] = acc[mt][nt][r];
    __syncthreads();

    // phase 2: tid = il*32 + oo*4 + ch
    const int ch = tid & 3, oo = (tid >> 2) & 7, il = tid >> 5;
    const int ival = i0 + il;
    const int gi = (ival < IC) ? ival : IC - 1;
    const unsigned short* Wt = Wbf + (size_t)(oo * 16 + ch * 4) * KP + (size_t)gi * 8;

    float wreg[4][8];
#pragma unroll
    for (int c = 0; c < 4; ++c) {
        union { short8 v; unsigned short h[8]; } uw;
        uw.v = *(const short8*)(Wt + (size_t)c * KP);
#pragma unroll
        for (int j = 0; j < 8; ++j) wreg[c][j] = bf2f(uw.h[j]);
    }
    float p = 0.0f;
#pragma unroll
    for (int c = 0; c < 4; ++c) {
        const float* hr = &Hs[(oo * 16 + ch * 4 + c) * 68 + il * 8];
        const float4 h0 = *(const float4*)hr;
        const float4 h1 = *(const float4*)(hr + 4);
        p = fmaf(wreg[c][0], h0.x, p); p = fmaf(wreg[c][1], h0.y, p);
        p = fmaf(wreg[c][2], h0.z, p); p = fmaf(wreg[c][3], h0.w, p);
        p = fmaf(wreg[c][4], h1.x, p); p = fmaf(wreg[c][5], h1.y, p);
        p = fmaf(wreg[c][6], h1.z, p); p = fmaf(wreg[c][7], h1.w, p);
    }
    p += __shfl_xor(p, 1); p += __shfl_xor(p, 2);   // combine ch quarters
    const float anew = p * (1.0f / 256.0f);
    float bv = anew;
    if (!first) bv += bij[gi * 8 + oo];
    float mx = bv;                                   // softmax over oo (bits 2..4)
    mx = fmaxf(mx, __shfl_xor(mx, 4));
    mx = fmaxf(mx, __shfl_xor(mx, 8));
    mx = fmaxf(mx, __shfl_xor(mx, 16));
    const float e = expf(bv - mx);
    float ss = e;
    ss += __shfl_xor(ss, 4); ss += __shfl_xor(ss, 8); ss += __shfl_xor(ss, 16);
    float cv = e / ss;
    if (ival >= IC) cv = 0.0f;                       // keep cwt pad rows zero
    if (ch == 0 && ival < IC) bij[ival * 8 + oo] = bv;
#pragma unroll
    for (int c = 0; c < 4; ++c) {
        union { short8 v; unsigned short h[8]; } o;
#pragma unroll
        for (int j = 0; j < 8; ++j) o.h[j] = f2bf(cv * wreg[c][j]);
        *(short8*)(cwt + (size_t)(oo * 16 + ch * 4 + c) * KP + (size_t)ival * 8) = o.v;
    }
}

// ---------------- fused cooperative routing kernel: all 3 iterations, 1 launch.
__global__ __launch_bounds__(256, 1)
void routing_kernel(const unsigned short* __restrict__ xT,
                    const unsigned short* __restrict__ xB,
                    const unsigned short* __restrict__ Wbf,
                    unsigned short* __restrict__ cwt,
                    float* __restrict__ spart,
                    unsigned short* __restrict__ vT,
                    float* __restrict__ bij,
                    float* __restrict__ out)
{
    cg::grid_group grid = cg::this_grid();
    __shared__ __align__(16) char sm[128 * 68 * 4];   // 34816 B, reused per phase
    const int tid = threadIdx.x;
    const int bid = blockIdx.x;

#pragma unroll 1
    for (int iter = 0; iter < 3; ++iter) {
        s_phase(sm, tid, bid, xB, cwt, spart);
        grid.sync();
        q_phase(sm, tid, bid, (iter < 2) ? 1 : 0, spart, out, vT);
        if (iter == 2) return;
        grid.sync();
        for (int t = bid; t < KTILES; t += 256)
            a_phase(sm, tid, t, (iter == 0) ? 1 : 0, xT, vT, Wbf, bij, cwt);
        grid.sync();
    }
}

// ---------------- classic-launch fallback wrappers (same device bodies)
__global__ __launch_bounds__(256, 2)
void s_gemm_k(const unsigned short* __restrict__ xB, const unsigned short* __restrict__ cwt,
              float* __restrict__ spart)
{
    __shared__ __align__(16) char sm[24576];
    s_phase(sm, threadIdx.x, blockIdx.x, xB, cwt, spart);
}

__global__ __launch_bounds__(256)
void squash_k(const float* __restrict__ spart, float* __restrict__ vout,
              unsigned short* __restrict__ vT, int writeT)
{
    __shared__ __align__(16) char sm[1024];
    q_phase(sm, threadIdx.x, blockIdx.x, writeT, spart, vout, vT);
}

__global__ __launch_bounds__(256, 2)
void a_gemm_k(const unsigned short* __restrict__ xT, const unsigned short* __restrict__ vT,
              const unsigned short* __restrict__ Wbf, float* __restrict__ bij,
              unsigned short* __restrict__ cwt, int first)
{
    __shared__ __align__(16) char sm[34816];
    for (int t = blockIdx.x; t < KTILES; t += gridDim.x)
        a_phase(sm, threadIdx.x, t, first, xT, vT, Wbf, bij, cwt);
}

extern "C" void kernel_launch(void* const* d_in, const int* in_sizes, int n_in,
                              void* d_out, int out_size, void* d_ws, size_t ws_size,
                              hipStream_t stream)
{
    const float* x = (const float*)d_in[0];   // [256, 2401, 8]
    const float* W = (const float*)d_in[1];   // [2401, 8, 16, 8]
    float* out = (float*)d_out;               // [256, 8, 16]

    char* p = (char*)d_ws;
    float*          spart = (float*)p;          p += (size_t)NI * BSZ * OCC * 4;   // 8.39 MB
    unsigned short* xT    = (unsigned short*)p; p += (size_t)KP * 256 * 2;         // 9.86 MB
    unsigned short* xB    = (unsigned short*)p; p += (size_t)256 * KP * 2;         // 9.86 MB
    unsigned short* Wbf   = (unsigned short*)p; p += (size_t)128 * KP * 2;         // 4.93 MB
    unsigned short* cwt   = (unsigned short*)p; p += (size_t)128 * KP * 2;         // 4.93 MB
    unsigned short* vT    = (unsigned short*)p; p += (size_t)128 * 256 * 2;        // 64 KB
    float*          bij   = (float*)p;                                            // 77 KB

    prep_kernel<<<1505, 256, 0, stream>>>(x, W, xT, xB, Wbf, cwt);

    void* kargs[] = { (void*)&xT, (void*)&xB, (void*)&Wbf, (void*)&cwt,
                      (void*)&spart, (void*)&vT, (void*)&bij, (void*)&out };
    hipError_t err = hipLaunchCooperativeKernel((void*)routing_kernel,
                                                dim3(256), dim3(256), kargs, 0, stream);
    if (err != hipSuccess) {
        // fallback: classic 8-launch pipeline (identical math)
        s_gemm_k<<<256, 256, 0, stream>>>(xB, cwt, spart);
        squash_k<<<256, 256, 0, stream>>>(spart, nullptr, vT, 1);
        a_gemm_k<<<256, 256, 0, stream>>>(xT, vT, Wbf, bij, cwt, 1);
        s_gemm_k<<<256, 256, 0, stream>>>(xB, cwt, spart);
        squash_k<<<256, 256, 0, stream>>>(spart, nullptr, vT, 1);
        a_gemm_k<<<256, 256, 0, stream>>>(xT, vT, Wbf, bij, cwt, 0);
        s_gemm_k<<<256, 256, 0, stream>>>(xB, cwt, spart);
        squash_k<<<256, 256, 0, stream>>>(spart, out, vT, 0);
    }
}

// Round 2
// 141.283 us; speedup vs baseline: 2.6959x; 2.6959x over previous
//
#include <hip/hip_runtime.h>
#include <math.h>

#define IC     2401
#define BSZ    256
#define OC     8
#define CS     16
#define OCC    128     // OC*CS
#define XROW   19208   // x row length (floats) = IC*8
#define KP     19264   // padded K (=301*64 = 2408 granules of 8), pad zeroed
#define KTILES 301
#define NI     128     // split-K slices for s_gemm (512 blocks -> 2 blocks/CU)

typedef __attribute__((ext_vector_type(8))) short short8;
typedef __attribute__((ext_vector_type(4))) float f32x4;

__device__ __forceinline__ unsigned short f2bf(float f) {
    union { float f; unsigned u; } v; v.f = f;
    const unsigned r = v.u + 0x7FFF + ((v.u >> 16) & 1);   // RNE
    return (unsigned short)(r >> 16);
}
__device__ __forceinline__ float bf2f(unsigned short h) {
    union { unsigned u; float f; } v; v.u = ((unsigned)h) << 16;
    return v.f;
}

// ---------------- prep (one launch): blocks 0..1203 -> xT + xB ; 1204..1504 -> Wbf + cwt0
__global__ __launch_bounds__(256)
void prep_kernel(const float* __restrict__ x, const float* __restrict__ W,
                 unsigned short* __restrict__ xT, unsigned short* __restrict__ xB,
                 unsigned short* __restrict__ Wbf, unsigned short* __restrict__ cwt)
{
    const int tid = threadIdx.x;
    if (blockIdx.x < 1204) {
        __shared__ float Ts[64 * 65];
        const int bg = blockIdx.x & 3;       // b-group of 64
        const int kt = blockIdx.x >> 2;      // k-tile 0..300
#pragma unroll
        for (int r = 0; r < 4; ++r) {
            const int flat = r * 256 + tid;  // 1024 float4s
            const int b = flat >> 4, cq = flat & 15;
            const int col = kt * 64 + cq * 4;
            float4 v = make_float4(0.f, 0.f, 0.f, 0.f);
            if (col < XROW) v = *(const float4*)(x + (size_t)(bg * 64 + b) * XROW + col);
            *(float4*)&Ts[b * 65 + cq * 4] = v;
        }
        __syncthreads();
        // xT[k][b] (transposed)
#pragma unroll
        for (int r = 0; r < 2; ++r) {
            const int flat = r * 256 + tid;  // 512 granules
            const int rl = flat >> 3, bq = flat & 7;
            union { short8 v; unsigned short h[8]; } o;
#pragma unroll
            for (int j = 0; j < 8; ++j) o.h[j] = f2bf(Ts[(bq * 8 + j) * 65 + rl]);
            *(short8*)(xT + (size_t)(kt * 64 + rl) * 256 + bg * 64 + bq * 8) = o.v;
        }
        // xB[b][k] (row-major bf16, padded)
#pragma unroll
        for (int r = 0; r < 2; ++r) {
            const int flat = r * 256 + tid;  // 512 granules
            const int b = flat >> 3, g = flat & 7;
            union { short8 v; unsigned short h[8]; } o;
#pragma unroll
            for (int j = 0; j < 8; ++j) o.h[j] = f2bf(Ts[b * 65 + g * 8 + j]);
            *(short8*)(xB + (size_t)(bg * 64 + b) * KP + (size_t)kt * 64 + g * 8) = o.v;
        }
    } else {
        __shared__ float Ws[8 * 1032];
        const int i0 = (blockIdx.x - 1204) * 8;
#pragma unroll
        for (int r = 0; r < 8; ++r) {
            const int flat = r * 256 + tid;  // 2048 float4s
            const int g = flat >> 8, rem = flat & 255;
            int gi = i0 + g; if (gi > 2400) gi = 2400;
            const float4 v = *(const float4*)(W + (size_t)gi * 1024 + rem * 4);
            *(float4*)&Ws[g * 1032 + rem * 4] = v;
        }
        __syncthreads();
#pragma unroll
        for (int r = 0; r < 4; ++r) {
            const int flat = r * 256 + tid;  // 1024 granules
            const int oc = flat >> 3, g = flat & 7;
            const int gi = i0 + g;
            union { short8 v; unsigned short h[8]; } w, c;
            if (gi <= 2400) {
                const float* wp = &Ws[g * 1032 + oc * 8];
#pragma unroll
                for (int j = 0; j < 8; ++j) {
                    w.h[j] = f2bf(wp[j]);
                    c.h[j] = f2bf(0.125f * wp[j]);
                }
            } else {
#pragma unroll
                for (int j = 0; j < 8; ++j) { w.h[j] = 0; c.h[j] = 0; }
            }
            *(short8*)(Wbf + (size_t)oc * KP + (size_t)gi * 8) = w.v;
            *(short8*)(cwt + (size_t)oc * KP + (size_t)gi * 8) = c.v;
        }
    }
}

// ---------------- s partials: spart[iy][b][oc] = sum_k xB[b,k]*cwt[oc,k]
// grid (4 bg, NI), 256 thr = 4 waves. Block 64b x 128oc; wave 32b x 64oc (2m x 4n).
// Register double-buffer: prefetch next K-tile during MFMA of current.
__global__ __launch_bounds__(256, 2)
void s_gemm(const unsigned short* __restrict__ xB, const unsigned short* __restrict__ cwt,
            float* __restrict__ spart)
{
    __shared__ __align__(16) unsigned short Xs[64 * 64];    // 8 KB
    __shared__ __align__(16) unsigned short Bs[128 * 64];   // 16 KB
    const int tid = threadIdx.x;
    const int bg  = blockIdx.x, iy = blockIdx.y;
    const int b0  = bg * 64;
    const int ln  = tid & 63;
    const int mr  = ln & 15, qd = ln >> 4;
    const int mh  = (tid >> 6) & 1;        // m-half (32 b-rows)
    const int nh  = tid >> 7;              // n-half (64 oc)

    f32x4 acc[2][4];
#pragma unroll
    for (int a = 0; a < 2; ++a)
#pragma unroll
        for (int b = 0; b < 4; ++b) acc[a][b] = (f32x4){0.f, 0.f, 0.f, 0.f};

    // staging addresses: row = r*32 + (tid>>3), col granule = tid&7
    const int srow = tid >> 3, scol = tid & 7;
    const int ssw  = (scol ^ (srow & 7)) * 8;              // same for all r (32 % 8 == 0)
    const unsigned short* xp0 = xB  + (size_t)(b0 + srow) * KP + (size_t)scol * 8;
    const unsigned short* bp0 = cwt + (size_t)srow * KP + (size_t)scol * 8;

    short8 vx[2], vb[4];
    int kt = iy;
#pragma unroll
    for (int r = 0; r < 2; ++r) vx[r] = *(const short8*)(xp0 + (size_t)r * 32 * KP + (size_t)kt * 64);
#pragma unroll
    for (int r = 0; r < 4; ++r) vb[r] = *(const short8*)(bp0 + (size_t)r * 32 * KP + (size_t)kt * 64);

    while (true) {
        __syncthreads();
#pragma unroll
        for (int r = 0; r < 2; ++r) *(short8*)&Xs[(r * 32 + srow) * 64 + ssw] = vx[r];
#pragma unroll
        for (int r = 0; r < 4; ++r) *(short8*)&Bs[(r * 32 + srow) * 64 + ssw] = vb[r];
        const int ktn = kt + NI;
        if (ktn < KTILES) {
#pragma unroll
            for (int r = 0; r < 2; ++r) vx[r] = *(const short8*)(xp0 + (size_t)r * 32 * KP + (size_t)ktn * 64);
#pragma unroll
            for (int r = 0; r < 4; ++r) vb[r] = *(const short8*)(bp0 + (size_t)r * 32 * KP + (size_t)ktn * 64);
        }
        __syncthreads();
#pragma unroll
        for (int kk = 0; kk < 2; ++kk) {
            const int csw = ((kk * 4 + qd) ^ (mr & 7)) * 8;
            const short8 a0 = *(const short8*)&Xs[(mh * 32 + mr) * 64 + csw];
            const short8 a1 = *(const short8*)&Xs[(mh * 32 + 16 + mr) * 64 + csw];
#pragma unroll
            for (int nt = 0; nt < 4; ++nt) {
                const short8 b = *(const short8*)&Bs[(nh * 64 + nt * 16 + mr) * 64 + csw];
                acc[0][nt] = __builtin_amdgcn_mfma_f32_16x16x32_bf16(a0, b, acc[0][nt], 0, 0, 0);
                acc[1][nt] = __builtin_amdgcn_mfma_f32_16x16x32_bf16(a1, b, acc[1][nt], 0, 0, 0);
            }
        }
        if (ktn >= KTILES) break;
        kt = ktn;
    }

    float* op = spart + ((size_t)iy * BSZ + b0) * OCC;
#pragma unroll
    for (int mt = 0; mt < 2; ++mt)
#pragma unroll
        for (int nt = 0; nt < 4; ++nt)
#pragma unroll
            for (int r = 0; r < 4; ++r)
                op[(size_t)(mh * 32 + mt * 16 + qd * 4 + r) * OCC + nh * 64 + nt * 16 + mr]
                    = acc[mt][nt][r];
}

// ---------------- reduce NI split-K partials + squash, full-chip spread.
// grid 256 blocks x 256 thr; block = 8 (b,o)-rows; 2-way k split per element.
__global__ __launch_bounds__(256)
void squash_kernel(const float* __restrict__ spart, float* __restrict__ vout,
                   unsigned short* __restrict__ vT, int writeT)
{
    __shared__ float red[256];
    const int tid = threadIdx.x;
    const int r0  = blockIdx.x * 8;          // first of 8 rows (row = b*8+o)
    const int idx = tid & 127;               // element within 8x16 chunk
    const int k0  = tid >> 7;                // k parity

    const float* base = spart + (size_t)r0 * 16 + idx;
    float acc = 0.0f;
#pragma unroll 8
    for (int k = k0; k < NI; k += 2) acc += base[(size_t)k * (BSZ * OCC)];
    red[tid] = acc;
    __syncthreads();

    if (tid < 128) {
        const float s = red[tid] + red[tid + 128];
        float ms = s * s;
        ms += __shfl_xor(ms, 1); ms += __shfl_xor(ms, 2);
        ms += __shfl_xor(ms, 4); ms += __shfl_xor(ms, 8);
        const float scale = sqrtf(ms) / (1.0f + ms);   // == mag_sq/(1+mag_sq)/mag
        const float outv = s * scale;
        const int row = r0 + (tid >> 4);     // = b*8 + o
        const int j   = tid & 15;
        if (writeT) {
            vT[(size_t)((row & 7) * 16 + j) * 256 + (row >> 3)] = f2bf(outv);
        } else {
            vout[(size_t)row * 16 + j] = outv;
        }
    }
}

// ---------------- agreement (MFMA) + bij + softmax + write cwt for next iter.
// Block = 8 i's. Phase 1: H[oc][(i,d)] = sum_b vT[oc][b]*xT[(i,d)][b].
// Phase 2: a[i,o] = (1/256) sum_{c,d} Wbf*H; softmax over o; cwt = c*Wbf.
// Register double-buffer over the 4 batch chunks.
template<bool FIRST>
__global__ __launch_bounds__(256, 2)
void a_gemm(const unsigned short* __restrict__ xT, const unsigned short* __restrict__ vT,
            const unsigned short* __restrict__ Wbf, float* __restrict__ bij,
            unsigned short* __restrict__ cwt)
{
    __shared__ __align__(16) char smraw[128 * 68 * 4];      // 34816 B (staging aliased)
    unsigned short* As = (unsigned short*)smraw;            // [128 oc][64 b]
    unsigned short* Bx = (unsigned short*)(smraw + 16384);  // [64 (i,d)][64 b]
    float* Hs = (float*)smraw;                              // [128][68]

    const int tid = threadIdx.x;
    const int i0  = blockIdx.x * 8;
    const int ln  = tid & 63, wv = tid >> 6;
    const int mr  = ln & 15, qd = ln >> 4;

    f32x4 acc[2][4];
#pragma unroll
    for (int a = 0; a < 2; ++a)
#pragma unroll
        for (int b = 0; b < 4; ++b) acc[a][b] = (f32x4){0.f, 0.f, 0.f, 0.f};

    const int srow = tid >> 3, scol = tid & 7;
    const int ssw  = (scol ^ (srow & 7)) * 8;
    const unsigned short* ap0 = vT + (size_t)srow * 256 + (size_t)scol * 8;
    const unsigned short* bp0 = xT + (size_t)(i0 * 8 + srow) * 256 + (size_t)scol * 8;

    short8 va[4], vbx[2];
#pragma unroll
    for (int r = 0; r < 4; ++r) va[r]  = *(const short8*)(ap0 + (size_t)r * 32 * 256);
#pragma unroll
    for (int r = 0; r < 2; ++r) vbx[r] = *(const short8*)(bp0 + (size_t)r * 32 * 256);

    for (int bc = 0; bc < 4; ++bc) {
        __syncthreads();
#pragma unroll
        for (int r = 0; r < 4; ++r) *(short8*)&As[(r * 32 + srow) * 64 + ssw] = va[r];
#pragma unroll
        for (int r = 0; r < 2; ++r) *(short8*)&Bx[(r * 32 + srow) * 64 + ssw] = vbx[r];
        if (bc < 3) {
#pragma unroll
            for (int r = 0; r < 4; ++r) va[r]  = *(const short8*)(ap0 + (size_t)r * 32 * 256 + (bc + 1) * 64);
#pragma unroll
            for (int r = 0; r < 2; ++r) vbx[r] = *(const short8*)(bp0 + (size_t)r * 32 * 256 + (bc + 1) * 64);
        }
        __syncthreads();
#pragma unroll
        for (int kk = 0; kk < 2; ++kk) {
            const int csw = ((kk * 4 + qd) ^ (mr & 7)) * 8;
#pragma unroll
            for (int nt = 0; nt < 4; ++nt) {
                const short8 b = *(const short8*)&Bx[(nt * 16 + mr) * 64 + csw];
#pragma unroll
                for (int mt = 0; mt < 2; ++mt) {
                    const short8 a = *(const short8*)&As[((wv * 2 + mt) * 16 + mr) * 64 + csw];
                    acc[mt][nt] = __builtin_amdgcn_mfma_f32_16x16x32_bf16(a, b, acc[mt][nt], 0, 0, 0);
                }
            }
        }
    }

    __syncthreads();
#pragma unroll
    for (int mt = 0; mt < 2; ++mt)
#pragma unroll
        for (int nt = 0; nt < 4; ++nt)
#pragma unroll
            for (int r = 0; r < 4; ++r)
                Hs[((wv * 2 + mt) * 16 + qd * 4 + r) * 68 + nt * 16 + mr] = acc[mt][nt][r];
    __syncthreads();

    // phase 2: tid = il*32 + oo*4 + ch
    const int ch = tid & 3, oo = (tid >> 2) & 7, il = tid >> 5;
    const int ival = i0 + il;
    const int gi = (ival < IC) ? ival : IC - 1;
    const unsigned short* Wt = Wbf + (size_t)(oo * 16 + ch * 4) * KP + (size_t)gi * 8;

    float wreg[4][8];
#pragma unroll
    for (int c = 0; c < 4; ++c) {
        union { short8 v; unsigned short h[8]; } uw;
        uw.v = *(const short8*)(Wt + (size_t)c * KP);
#pragma unroll
        for (int j = 0; j < 8; ++j) wreg[c][j] = bf2f(uw.h[j]);
    }
    float p = 0.0f;
#pragma unroll
    for (int c = 0; c < 4; ++c) {
        const float* hr = &Hs[(oo * 16 + ch * 4 + c) * 68 + il * 8];
        const float4 h0 = *(const float4*)hr;
        const float4 h1 = *(const float4*)(hr + 4);
        p = fmaf(wreg[c][0], h0.x, p); p = fmaf(wreg[c][1], h0.y, p);
        p = fmaf(wreg[c][2], h0.z, p); p = fmaf(wreg[c][3], h0.w, p);
        p = fmaf(wreg[c][4], h1.x, p); p = fmaf(wreg[c][5], h1.y, p);
        p = fmaf(wreg[c][6], h1.z, p); p = fmaf(wreg[c][7], h1.w, p);
    }
    p += __shfl_xor(p, 1); p += __shfl_xor(p, 2);   // combine ch quarters
    const float anew = p * (1.0f / 256.0f);
    float bv = anew;
    if (!FIRST) bv += bij[gi * 8 + oo];
    float mx = bv;                                   // softmax over oo (bits 2..4)
    mx = fmaxf(mx, __shfl_xor(mx, 4));
    mx = fmaxf(mx, __shfl_xor(mx, 8));
    mx = fmaxf(mx, __shfl_xor(mx, 16));
    const float e = expf(bv - mx);
    float ss = e;
    ss += __shfl_xor(ss, 4); ss += __shfl_xor(ss, 8); ss += __shfl_xor(ss, 16);
    float cv = e / ss;
    if (ival >= IC) cv = 0.0f;                       // keep cwt pad rows zero
    if (ch == 0 && ival < IC) bij[ival * 8 + oo] = bv;
#pragma unroll
    for (int c = 0; c < 4; ++c) {
        union { short8 v; unsigned short h[8]; } o;
#pragma unroll
        for (int j = 0; j < 8; ++j) o.h[j] = f2bf(cv * wreg[c][j]);
        *(short8*)(cwt + (size_t)(oo * 16 + ch * 4 + c) * KP + (size_t)ival * 8) = o.v;
    }
}

extern "C" void kernel_launch(void* const* d_in, const int* in_sizes, int n_in,
                              void* d_out, int out_size, void* d_ws, size_t ws_size,
                              hipStream_t stream)
{
    const float* x = (const float*)d_in[0];   // [256, 2401, 8]
    const float* W = (const float*)d_in[1];   // [2401, 8, 16, 8]
    float* out = (float*)d_out;               // [256, 8, 16]

    char* p = (char*)d_ws;
    float*          spart = (float*)p;          p += (size_t)NI * BSZ * OCC * 4;   // 16.8 MB
    unsigned short* xT    = (unsigned short*)p; p += (size_t)KP * 256 * 2;         // 9.86 MB
    unsigned short* xB    = (unsigned short*)p; p += (size_t)256 * KP * 2;         // 9.86 MB
    unsigned short* Wbf   = (unsigned short*)p; p += (size_t)128 * KP * 2;         // 4.93 MB
    unsigned short* cwt   = (unsigned short*)p; p += (size_t)128 * KP * 2;         // 4.93 MB
    unsigned short* vT    = (unsigned short*)p; p += (size_t)128 * 256 * 2;        // 64 KB
    float*          bij   = (float*)p;                                            // 77 KB

    const dim3 sgrid(4, NI);

    prep_kernel<<<1505, 256, 0, stream>>>(x, W, xT, xB, Wbf, cwt);

    // iter 0
    s_gemm<<<sgrid, 256, 0, stream>>>(xB, cwt, spart);
    squash_kernel<<<256, 256, 0, stream>>>(spart, nullptr, vT, 1);
    a_gemm<true><<<KTILES, 256, 0, stream>>>(xT, vT, Wbf, bij, cwt);
    // iter 1
    s_gemm<<<sgrid, 256, 0, stream>>>(xB, cwt, spart);
    squash_kernel<<<256, 256, 0, stream>>>(spart, nullptr, vT, 1);
    a_gemm<false><<<KTILES, 256, 0, stream>>>(xT, vT, Wbf, bij, cwt);
    // iter 2 (final)
    s_gemm<<<sgrid, 256, 0, stream>>>(xB, cwt, spart);
    squash_kernel<<<256, 256, 0, stream>>>(spart, out, vT, 0);
}